// Round 22
// baseline (285.760 us; speedup 1.0000x reference)
//
#include <hip/hip_runtime.h>
#include <stdint.h>

#define DD 128
#define LDSROW 136  // 128 cols + 8 pad (ushort) -> 272B row stride

typedef __attribute__((ext_vector_type(8))) short short8;
typedef __attribute__((ext_vector_type(4))) float float4v;

// ---------- bf16 helpers (RTNE) ----------
__device__ __forceinline__ unsigned short f2bf(float f) {
  unsigned u = __float_as_uint(f);
  unsigned r = u + 0x7fffu + ((u >> 16) & 1u);
  return (unsigned short)(r >> 16);
}
__device__ __forceinline__ unsigned pack2(float a, float b) {
  return (unsigned)f2bf(a) | ((unsigned)f2bf(b) << 16);
}
__device__ __forceinline__ float2 unpack2(unsigned p) {
  float2 r;
  r.x = __uint_as_float(p << 16);
  r.y = __uint_as_float(p & 0xffff0000u);
  return r;
}

// ---------- CSR build pass A: deg atomics + per-edge rank (ushort) + weight prep fused ----------
__global__ __launch_bounds__(256) void k_deg_prep(const int* __restrict__ dst, int* deg,
                                                  unsigned short* __restrict__ erank,
                                                  int e, int eb,
                                                  const float* __restrict__ W1, const float* __restrict__ W2,
                                                  const float* __restrict__ Wself, const float* __restrict__ Wneigh,
                                                  unsigned* __restrict__ wfrag) {
  int b = blockIdx.x;
  if (b < eb) {
    int i = b * 256 + threadIdx.x;
    if (i < e) erank[i] = (unsigned short)atomicAdd(&deg[dst[i]], 1);
  } else {
    int gid = (b - eb) * 256 + threadIdx.x;  // 0 .. 65535
    int m = gid >> 13;
    int r = gid & 8191;
    int p = r & 3;
    int lane = (r >> 2) & 63;
    int t = (r >> 8) & 3;
    int c = r >> 10;
    const float* W;
    if (m == 0) W = W1;
    else if (m == 1) W = W2;
    else if (m < 5) W = Wself + (size_t)(m - 2) * DD * DD;
    else W = Wneigh + (size_t)(m - 5) * DD * DD;
    int n = c * 16 + (lane & 15);
    int k = t * 32 + (lane >> 4) * 8 + 2 * p;
    wfrag[gid] = pack2(W[(size_t)k * DD + n], W[(size_t)(k + 1) * DD + n]);
  }
}

__global__ __launch_bounds__(1024) void k_scan1(const int* __restrict__ deg, int* __restrict__ incl,
                                                int* __restrict__ bsum, int n) {
  __shared__ int sh[1024];
  int t = threadIdx.x;
  int i = blockIdx.x * 1024 + t;
  int v = (i < n) ? deg[i] : 0;
  sh[t] = v;
  __syncthreads();
#pragma unroll
  for (int off = 1; off < 1024; off <<= 1) {
    int add = (t >= off) ? sh[t - off] : 0;
    __syncthreads();
    sh[t] += add;
    __syncthreads();
  }
  if (i < n) incl[i] = sh[t];
  if (t == 1023) bsum[blockIdx.x] = sh[1023];
}

__global__ __launch_bounds__(1024) void k_scan3(const int* __restrict__ deg, const int* __restrict__ incl,
                                                const int* __restrict__ bsum, int* __restrict__ rowstart,
                                                int n, int nb) {
  __shared__ int sboff;
  int t = threadIdx.x;
  if (t < 64) {
    int orig = (t < nb) ? bsum[t] : 0;
    int v = orig;
#pragma unroll
    for (int off = 1; off < 64; off <<= 1) {
      int u = __shfl_up(v, off);
      if (t >= off) v += u;
    }
    if (t == (int)blockIdx.x) sboff = v - orig;
  }
  __syncthreads();
  int i = blockIdx.x * 1024 + t;
  if (i >= n) return;
  int d = deg[i];
  int excl = sboff + incl[i] - d;
  rowstart[i] = excl;
  if (i == n - 1) rowstart[n] = excl + d;
}

// ---------- merged: fused fc_in GEMM (blocks [0,gb)) + atomic-free CSR fill (blocks [gb,gb+fb)) ----------
__global__ __launch_bounds__(256) void k_fill_fc(const int* __restrict__ src, const int* __restrict__ dst,
                                                 const unsigned short* __restrict__ erank,
                                                 const int* __restrict__ rowstart,
                                                 unsigned short* __restrict__ esrc, int e, int gb,
                                                 const float* __restrict__ h,
                                                 const uint4* __restrict__ wf1, const uint4* __restrict__ wf2,
                                                 const float* __restrict__ b1, const float* __restrict__ b2,
                                                 unsigned short* __restrict__ outbf, int n) {
  __shared__ unsigned short sT[64 * LDSROW];
  int b = blockIdx.x;
  if (b >= gb) {
    int i = (b - gb) * 256 + threadIdx.x;
    if (i < e) {
      int d = dst[i];
      int p = rowstart[d] + (int)erank[i];
      esrc[p] = (unsigned short)src[i];
    }
    return;
  }
  // ---- fc12 body ----
  int tid = threadIdx.x, w = tid >> 6, lane = tid & 63;
  int q = lane >> 4, nn = lane & 15;
  int r0 = (b * 4 + w) * 16;
  int rr = r0 + nn; if (rr >= n) rr = n - 1;
  short8 a[4];
  {
    const float* X = h + (size_t)rr * DD;
#pragma unroll
    for (int t = 0; t < 4; ++t) {
      int k0 = t * 32 + q * 8;
      float4 f0 = *(const float4*)&X[k0];
      float4 f1 = *(const float4*)&X[k0 + 4];
      uint4 u;
      u.x = pack2(f0.x, f0.y); u.y = pack2(f0.z, f0.w);
      u.z = pack2(f1.x, f1.y); u.w = pack2(f1.z, f1.w);
      a[t] = __builtin_bit_cast(short8, u);
    }
  }
  float4v acc[8];
#pragma unroll
  for (int c = 0; c < 8; ++c) acc[c] = (float4v){0.f, 0.f, 0.f, 0.f};
#pragma unroll
  for (int c = 0; c < 8; ++c) {
#pragma unroll
    for (int t = 0; t < 4; ++t) {
      short8 bb = __builtin_bit_cast(short8, wf1[(c * 4 + t) * 64 + lane]);
      acc[c] = __builtin_amdgcn_mfma_f32_16x16x32_bf16(a[t], bb, acc[c], 0, 0, 0);
    }
  }
#pragma unroll
  for (int c = 0; c < 8; ++c) {
    float bc = b1[c * 16 + nn];
#pragma unroll
    for (int g = 0; g < 4; ++g) {
      int lr = w * 16 + q * 4 + g;
      sT[lr * LDSROW + c * 16 + nn] = f2bf(tanhf(acc[c][g] + bc));
    }
  }
  __syncthreads();
  short8 a2[4];
#pragma unroll
  for (int t = 0; t < 4; ++t) {
    const uint4* p = (const uint4*)&sT[(w * 16 + nn) * LDSROW + (t * 4 + q) * 8];
    a2[t] = __builtin_bit_cast(short8, *p);
  }
  float4v acc2[8];
#pragma unroll
  for (int c = 0; c < 8; ++c) acc2[c] = (float4v){0.f, 0.f, 0.f, 0.f};
#pragma unroll
  for (int c = 0; c < 8; ++c) {
#pragma unroll
    for (int t = 0; t < 4; ++t) {
      short8 bb = __builtin_bit_cast(short8, wf2[(c * 4 + t) * 64 + lane]);
      acc2[c] = __builtin_amdgcn_mfma_f32_16x16x32_bf16(a2[t], bb, acc2[c], 0, 0, 0);
    }
  }
#pragma unroll
  for (int c = 0; c < 8; ++c) {
    float bc = b2[c * 16 + nn];
#pragma unroll
    for (int g = 0; g < 4; ++g) {
      int row = r0 + q * 4 + g;
      if (row < n) outbf[(size_t)row * DD + c * 16 + nn] = f2bf(acc2[c][g] + bc);
    }
  }
}

// ---------- fused layer, 16 rows/block: aggregate (1 row per 16-lane group, 2-deep pipelined 8-wide batches,
// masked tail) -> LDS -> SAGE GEMM.  ACT: 1 tanh, 2 silu
template <int ACT, bool OUTF32>
__global__ __launch_bounds__(256) void k_layer16(const uint4* __restrict__ X,
                                                 const int* __restrict__ rowstart,
                                                 const unsigned short* __restrict__ esrc,
                                                 const uint4* __restrict__ wfs, const uint4* __restrict__ wfn,
                                                 const float* __restrict__ bias, void* __restrict__ outp, int n) {
  __shared__ unsigned short sG[16 * LDSROW];
  int tid = threadIdx.x;
  int grp = tid >> 4, nn = tid & 15;   // 16 groups x 16 lanes
  int r0 = blockIdx.x * 16;
  int r = r0 + grp;
  // ---- phase 1: aggregate row r; lane nn covers bf16 cols nn*8..nn*8+7 (one uint4) ----
  if (r < n) {
    int beg = rowstart[r];
    int cnt = rowstart[r + 1] - beg;
    float acc[8];
#pragma unroll
    for (int i = 0; i < 8; ++i) acc[i] = 0.f;
    int base = 0;
    if (cnt >= 8) {
      // 2-deep software pipeline: batch B's gathers issue before batch A is consumed
      int j0 = beg;
      int s0 = esrc[j0], s1 = esrc[j0 + 1], s2 = esrc[j0 + 2], s3 = esrc[j0 + 3];
      int s4 = esrc[j0 + 4], s5 = esrc[j0 + 5], s6 = esrc[j0 + 6], s7 = esrc[j0 + 7];
      uint4 a0 = X[(size_t)s0 * 16 + nn], a1 = X[(size_t)s1 * 16 + nn];
      uint4 a2 = X[(size_t)s2 * 16 + nn], a3 = X[(size_t)s3 * 16 + nn];
      uint4 a4 = X[(size_t)s4 * 16 + nn], a5 = X[(size_t)s5 * 16 + nn];
      uint4 a6 = X[(size_t)s6 * 16 + nn], a7 = X[(size_t)s7 * 16 + nn];
      int nb2 = 8;
      for (; nb2 + 8 <= cnt; nb2 += 8) {
        int j1 = beg + nb2;
        int t0 = esrc[j1], t1 = esrc[j1 + 1], t2 = esrc[j1 + 2], t3 = esrc[j1 + 3];
        int t4 = esrc[j1 + 4], t5 = esrc[j1 + 5], t6 = esrc[j1 + 6], t7 = esrc[j1 + 7];
        uint4 b0 = X[(size_t)t0 * 16 + nn], b1 = X[(size_t)t1 * 16 + nn];
        uint4 b2 = X[(size_t)t2 * 16 + nn], b3 = X[(size_t)t3 * 16 + nn];
        uint4 b4 = X[(size_t)t4 * 16 + nn], b5 = X[(size_t)t5 * 16 + nn];
        uint4 b6 = X[(size_t)t6 * 16 + nn], b7 = X[(size_t)t7 * 16 + nn];
        {
          const unsigned* u0 = (const unsigned*)&a0;
          const unsigned* u1 = (const unsigned*)&a1;
          const unsigned* u2 = (const unsigned*)&a2;
          const unsigned* u3 = (const unsigned*)&a3;
          const unsigned* u4 = (const unsigned*)&a4;
          const unsigned* u5 = (const unsigned*)&a5;
          const unsigned* u6 = (const unsigned*)&a6;
          const unsigned* u7 = (const unsigned*)&a7;
#pragma unroll
          for (int k = 0; k < 4; ++k) {
            float2 f0 = unpack2(u0[k]), f1 = unpack2(u1[k]);
            float2 f2 = unpack2(u2[k]), f3 = unpack2(u3[k]);
            float2 f4 = unpack2(u4[k]), f5 = unpack2(u5[k]);
            float2 f6 = unpack2(u6[k]), f7 = unpack2(u7[k]);
            acc[2 * k]     += ((f0.x + f1.x) + (f2.x + f3.x)) + ((f4.x + f5.x) + (f6.x + f7.x));
            acc[2 * k + 1] += ((f0.y + f1.y) + (f2.y + f3.y)) + ((f4.y + f5.y) + (f6.y + f7.y));
          }
        }
        a0 = b0; a1 = b1; a2 = b2; a3 = b3;
        a4 = b4; a5 = b5; a6 = b6; a7 = b7;
      }
      {
        const unsigned* u0 = (const unsigned*)&a0;
        const unsigned* u1 = (const unsigned*)&a1;
        const unsigned* u2 = (const unsigned*)&a2;
        const unsigned* u3 = (const unsigned*)&a3;
        const unsigned* u4 = (const unsigned*)&a4;
        const unsigned* u5 = (const unsigned*)&a5;
        const unsigned* u6 = (const unsigned*)&a6;
        const unsigned* u7 = (const unsigned*)&a7;
#pragma unroll
        for (int k = 0; k < 4; ++k) {
          float2 f0 = unpack2(u0[k]), f1 = unpack2(u1[k]);
          float2 f2 = unpack2(u2[k]), f3 = unpack2(u3[k]);
          float2 f4 = unpack2(u4[k]), f5 = unpack2(u5[k]);
          float2 f6 = unpack2(u6[k]), f7 = unpack2(u7[k]);
          acc[2 * k]     += ((f0.x + f1.x) + (f2.x + f3.x)) + ((f4.x + f5.x) + (f6.x + f7.x));
          acc[2 * k + 1] += ((f0.y + f1.y) + (f2.y + f3.y)) + ((f4.y + f5.y) + (f6.y + f7.y));
        }
      }
      base = nb2;
    }
    if (base < cnt) {  // masked 8-wide tail: clamp index (dup gathers hit cache), weight 0/1
      int last = beg + cnt - 1;
      int j0 = beg + base;
      int i1 = j0 + 1 <= last ? j0 + 1 : last;
      int i2 = j0 + 2 <= last ? j0 + 2 : last;
      int i3 = j0 + 3 <= last ? j0 + 3 : last;
      int i4 = j0 + 4 <= last ? j0 + 4 : last;
      int i5 = j0 + 5 <= last ? j0 + 5 : last;
      int i6 = j0 + 6 <= last ? j0 + 6 : last;
      int i7 = j0 + 7 <= last ? j0 + 7 : last;
      float w1 = (base + 1 < cnt) ? 1.f : 0.f;
      float w2 = (base + 2 < cnt) ? 1.f : 0.f;
      float w3 = (base + 3 < cnt) ? 1.f : 0.f;
      float w4 = (base + 4 < cnt) ? 1.f : 0.f;
      float w5 = (base + 5 < cnt) ? 1.f : 0.f;
      float w6 = (base + 6 < cnt) ? 1.f : 0.f;
      float w7 = (base + 7 < cnt) ? 1.f : 0.f;
      int s0 = esrc[j0], s1 = esrc[i1], s2 = esrc[i2], s3 = esrc[i3];
      int s4 = esrc[i4], s5 = esrc[i5], s6 = esrc[i6], s7 = esrc[i7];
      uint4 v0 = X[(size_t)s0 * 16 + nn];
      uint4 v1 = X[(size_t)s1 * 16 + nn];
      uint4 v2 = X[(size_t)s2 * 16 + nn];
      uint4 v3 = X[(size_t)s3 * 16 + nn];
      uint4 v4 = X[(size_t)s4 * 16 + nn];
      uint4 v5 = X[(size_t)s5 * 16 + nn];
      uint4 v6 = X[(size_t)s6 * 16 + nn];
      uint4 v7 = X[(size_t)s7 * 16 + nn];
      const unsigned* u0 = (const unsigned*)&v0;
      const unsigned* u1 = (const unsigned*)&v1;
      const unsigned* u2 = (const unsigned*)&v2;
      const unsigned* u3 = (const unsigned*)&v3;
      const unsigned* u4 = (const unsigned*)&v4;
      const unsigned* u5 = (const unsigned*)&v5;
      const unsigned* u6 = (const unsigned*)&v6;
      const unsigned* u7 = (const unsigned*)&v7;
#pragma unroll
      for (int k = 0; k < 4; ++k) {
        float2 f0 = unpack2(u0[k]), f1 = unpack2(u1[k]);
        float2 f2 = unpack2(u2[k]), f3 = unpack2(u3[k]);
        float2 f4 = unpack2(u4[k]), f5 = unpack2(u5[k]);
        float2 f6 = unpack2(u6[k]), f7 = unpack2(u7[k]);
        acc[2 * k]     += ((f0.x + w1 * f1.x) + (w2 * f2.x + w3 * f3.x)) + ((w4 * f4.x + w5 * f5.x) + (w6 * f6.x + w7 * f7.x));
        acc[2 * k + 1] += ((f0.y + w1 * f1.y) + (w2 * f2.y + w3 * f3.y)) + ((w4 * f4.y + w5 * f5.y) + (w6 * f6.y + w7 * f7.y));
      }
    }
    float inv = 1.0f / (float)(cnt > 1 ? cnt : 1);
    uint4 o;
    o.x = pack2(acc[0] * inv, acc[1] * inv);
    o.y = pack2(acc[2] * inv, acc[3] * inv);
    o.z = pack2(acc[4] * inv, acc[5] * inv);
    o.w = pack2(acc[6] * inv, acc[7] * inv);
    *(uint4*)&sG[grp * LDSROW + nn * 8] = o;
  }
  __syncthreads();
  // ---- phase 2: SAGE GEMM on rows r0..r0+15. wave w -> col-chunks {2w, 2w+1} ----
  int w = tid >> 6, lane = tid & 63;
  int q = lane >> 4, nn16 = lane & 15;
  int rr = r0 + nn16; if (rr >= n) rr = n - 1;
  short8 a[4], gf[4];
  {
    const uint4* Xr = X + (size_t)rr * 16;
#pragma unroll
    for (int t = 0; t < 4; ++t) {
      a[t] = __builtin_bit_cast(short8, Xr[t * 4 + q]);
      gf[t] = __builtin_bit_cast(short8, *(const uint4*)&sG[nn16 * LDSROW + (t * 4 + q) * 8]);
    }
  }
  float4v acc2[2];
#pragma unroll
  for (int cc = 0; cc < 2; ++cc) acc2[cc] = (float4v){0.f, 0.f, 0.f, 0.f};
#pragma unroll
  for (int cc = 0; cc < 2; ++cc) {
    int c = 2 * w + cc;
#pragma unroll
    for (int t = 0; t < 4; ++t) {
      short8 b = __builtin_bit_cast(short8, wfs[(c * 4 + t) * 64 + lane]);
      acc2[cc] = __builtin_amdgcn_mfma_f32_16x16x32_bf16(a[t], b, acc2[cc], 0, 0, 0);
    }
#pragma unroll
    for (int t = 0; t < 4; ++t) {
      short8 b = __builtin_bit_cast(short8, wfn[(c * 4 + t) * 64 + lane]);
      acc2[cc] = __builtin_amdgcn_mfma_f32_16x16x32_bf16(gf[t], b, acc2[cc], 0, 0, 0);
    }
  }
#pragma unroll
  for (int cc = 0; cc < 2; ++cc) {
    int c = 2 * w + cc;
    float bc = bias[c * 16 + nn16];
#pragma unroll
    for (int gg = 0; gg < 4; ++gg) {
      int row = r0 + q * 4 + gg;
      if (row < n) {
        float v = acc2[cc][gg] + bc;
        if (ACT == 1) v = tanhf(v);
        else v = v / (1.f + __expf(-v));
        if (OUTF32) ((float*)outp)[(size_t)row * DD + c * 16 + nn16] = v;
        else ((unsigned short*)outp)[(size_t)row * DD + c * 16 + nn16] = f2bf(v);
      }
    }
  }
}

extern "C" void kernel_launch(void* const* d_in, const int* in_sizes, int n_in,
                              void* d_out, int out_size, void* d_ws, size_t ws_size,
                              hipStream_t stream) {
  const float* h_in = (const float*)d_in[0];
  const int* src    = (const int*)d_in[1];
  const int* dst    = (const int*)d_in[2];
  const float* W1   = (const float*)d_in[3];
  const float* b1   = (const float*)d_in[4];
  const float* W2   = (const float*)d_in[5];
  const float* b2   = (const float*)d_in[6];
  const float* Wself  = (const float*)d_in[7];
  const float* bself  = (const float*)d_in[8];
  const float* Wneigh = (const float*)d_in[9];
  const int N = in_sizes[0] / DD;
  const int E = in_sizes[1];
  float* out = (float*)d_out;

  char* ws = (char*)d_ws;
  size_t off = 0;
  auto alloc = [&](size_t bytes) -> char* {
    char* p = ws + off;
    off = (off + bytes + 255) & ~(size_t)255;
    return p;
  };
  unsigned* wfrag = (unsigned*)alloc(8 * 32768);
  unsigned* actA  = (unsigned*)alloc((size_t)N * 64 * 4);
  unsigned* actB  = (unsigned*)alloc((size_t)N * 64 * 4);
  unsigned short* esrc  = (unsigned short*)alloc((size_t)E * 2);
  unsigned short* erank = (unsigned short*)alloc((size_t)E * 2);
  int* degi     = (int*)alloc((size_t)N * 4);
  int* rowstart = (int*)alloc((size_t)(N + 1) * 4);
  int* incl     = (int*)alloc((size_t)N * 4);
  int* bsum     = (int*)alloc(65 * 4);

  hipMemsetAsync(degi, 0, (size_t)N * 4, stream);
  const int eb = (E + 255) / 256;
  const int nb = (N + 1023) / 1024;
  k_deg_prep<<<eb + 256, 256, 0, stream>>>(dst, degi, erank, E, eb, W1, W2, Wself, Wneigh, wfrag);
  k_scan1<<<nb, 1024, 0, stream>>>(degi, incl, bsum, N);
  k_scan3<<<nb, 1024, 0, stream>>>(degi, incl, bsum, rowstart, N, nb);

  const int gb = (N + 63) / 64;
  const int lb = (N + 15) / 16;
  const uint4* wf = (const uint4*)wfrag;

  // merged fc12 (first) + atomic-free ushort fill (behind)
  k_fill_fc<<<gb + eb, 256, 0, stream>>>(src, dst, erank, rowstart, esrc, E, gb,
                                         h_in, wf + 0 * 2048, wf + 1 * 2048, b1, b2,
                                         (unsigned short*)actB, N);

  const unsigned* cur = actB;
  unsigned* nxt = actA;
  for (int l = 0; l < 3; ++l) {
    const uint4* wsF = wf + (size_t)(2 + l) * 2048;
    const uint4* wnF = wf + (size_t)(5 + l) * 2048;
    const float* bs = bself + (size_t)l * DD;
    if (l < 2) {
      k_layer16<2, false><<<lb, 256, 0, stream>>>((const uint4*)cur, rowstart, esrc, wsF, wnF, bs, nxt, N);
      const unsigned* tmp = cur;
      cur = nxt;
      nxt = (unsigned*)tmp;
    } else {
      k_layer16<1, true><<<lb, 256, 0, stream>>>((const uint4*)cur, rowstart, esrc, wsF, wnF, bs, out, N);
    }
  }
}